// Round 4
// baseline (201.874 us; speedup 1.0000x reference)
//
#include <hip/hip_runtime.h>

// Problem constants
#define BATCH 32
#define NNODE 4096
#define CIN 32
#define COUT 64
#define KDEG 5
#define POOL 4
#define NNZ_E 65536
#define BC (BATCH * CIN)         // 1024 elems per node-row
#define TBF ((size_t)NNODE * BC) // elems per Chebyshev level (bf16 storage)
#define CAP 64                   // fixed bucket capacity per row (avg degree 16)

typedef short s16x8 __attribute__((ext_vector_type(8)));
typedef float f32x4 __attribute__((ext_vector_type(4)));
typedef unsigned long long u64;

// float -> bf16 bits, round-to-nearest-even
__device__ __forceinline__ unsigned short f2bf(float f) {
    union { float f; unsigned int u; } v; v.f = f;
    unsigned int u = v.u;
    u += 0x7fffu + ((u >> 16) & 1u);
    return (unsigned short)(u >> 16);
}
__device__ __forceinline__ float bf2f(unsigned short b) {
    union { float f; unsigned int u; } v; v.u = ((unsigned int)b) << 16;
    return v.f;
}
__device__ __forceinline__ u64 pack4(float a, float b, float c, float d) {
    return (u64)f2bf(a) | ((u64)f2bf(b) << 16) | ((u64)f2bf(c) << 32) | ((u64)f2bf(d) << 48);
}

// ---------------- prep2: transpose + W pack + capacity-bucket edge scatter -------
// (verified) Row r's edges land in es[r*64 .. r*64+cnt[r]) in arbitrary order
// (summation commutative). cnt zeroed by the preceding 16 KB memset.

__global__ void prep2_kernel(const float* __restrict__ x, unsigned short* __restrict__ t0,
                             const int* __restrict__ erow, const int* __restrict__ ecol,
                             const float* __restrict__ eval,
                             int* __restrict__ cnt, int2* __restrict__ es,
                             const float* __restrict__ W, unsigned short* __restrict__ WB) {
    int idx = blockIdx.x * 256 + threadIdx.x;   // [0, 1048576)
    // transpose [B][N][C] fp32 -> [N][B*C] bf16, 4 elems per thread
    int n   = idx >> 8;
    int rem = idx & 255;
    int b   = rem >> 3;
    int c4  = rem & 7;
    float4 v = ((const float4*)x)[(b * NNODE + n) * 8 + c4];
    ((u64*)t0)[idx] = pack4(v.x, v.y, v.z, v.w);

    if (idx < NNZ_E) {
        int r = erow[idx];
        int pos = atomicAdd(&cnt[r], 1);
        if (pos < CAP)
            es[(r << 6) + pos] = make_int2(ecol[idx], __float_as_int(eval[idx]));
    }

    if (idx < KDEG * COUT * CIN) {
        int c = idx & 31;
        int rest = idx >> 5;
        int o = rest & 63;
        int k = rest >> 6;
        // WB[k][o][c] : B-fragment order for mfma_16x16x32 (lane nn=o, kk=c)
        WB[idx] = f2bf(W[(c * KDEG + k) * COUT + o]);
    }
}

// ---------------- one (row, slice) unit of Chebyshev SpMM ----------------
// 8-deep unroll: deg~16 -> ONE iteration, 8 gathers in flight per lane
// (was 2 iterations x 4 -> halves the dependent-latency chain).
// Returns the packed bf16x4 result for (row r, u64-col sc) on ep==0 lanes.

__device__ __forceinline__ u64 spmm_row(
        const unsigned short* in, const unsigned short* sub,
        float scale, int has_sub, const int* cnt, const int2* es,
        int r, int sc, int ep) {
    const u64* in8 = (const u64*)in;
    int deg = cnt[r]; deg = deg > CAP ? CAP : deg;
    int beg = r << 6, end = beg + deg;

    float4 a0 = make_float4(0.f, 0.f, 0.f, 0.f);
    float4 a1 = a0, a2 = a0, a3 = a0;

    for (int base = beg + ep; base < end; base += 16) {
        float vv[8];
        u64   xx[8];
#pragma unroll
        for (int j = 0; j < 8; j++) {
            int idx = base + 2 * j;
            int src = idx < end ? idx : beg;   // beg valid: loop was entered
            int2 e = es[src];
            vv[j] = idx < end ? __int_as_float(e.y) : 0.f;
            xx[j] = in8[(size_t)e.x * 256 + sc];
        }
#define ACC4(A, J) \
        A.x += vv[J] * bf2f((unsigned short)xx[J]); \
        A.y += vv[J] * bf2f((unsigned short)(xx[J] >> 16)); \
        A.z += vv[J] * bf2f((unsigned short)(xx[J] >> 32)); \
        A.w += vv[J] * bf2f((unsigned short)(xx[J] >> 48));
        ACC4(a0, 0) ACC4(a1, 1) ACC4(a2, 2) ACC4(a3, 3)
        ACC4(a0, 4) ACC4(a1, 5) ACC4(a2, 6) ACC4(a3, 7)
#undef ACC4
    }

    float4 acc;
    acc.x = (a0.x + a1.x) + (a2.x + a3.x);
    acc.y = (a0.y + a1.y) + (a2.y + a3.y);
    acc.z = (a0.z + a1.z) + (a2.z + a3.z);
    acc.w = (a0.w + a1.w) + (a2.w + a3.w);

    // combine the two edge-parallel halves
    acc.x += __shfl_xor(acc.x, 32);
    acc.y += __shfl_xor(acc.y, 32);
    acc.z += __shfl_xor(acc.z, 32);
    acc.w += __shfl_xor(acc.w, 32);

    if (ep != 0) return 0;   // only ep==0 lanes produce the result

    size_t oi = (size_t)r * 256 + sc;
    float r0, r1, r2, r3;
    if (has_sub) {
        u64 sv = __builtin_nontemporal_load((const u64*)sub + oi);
        r0 = scale * acc.x - bf2f((unsigned short)sv);
        r1 = scale * acc.y - bf2f((unsigned short)(sv >> 16));
        r2 = scale * acc.z - bf2f((unsigned short)(sv >> 32));
        r3 = scale * acc.w - bf2f((unsigned short)(sv >> 48));
    } else {
        r0 = acc.x; r1 = acc.y; r2 = acc.z; r3 = acc.w;
    }
    return pack4(r0, r1, r2, r3);
}

// ---------------- standalone per-level SpMM (levels 1-3) ----------------
// grid = NNODE*2 = 8192 blocks; block = 4 rows x 1 slice (slice = bx&7 = XCD).

__global__ __launch_bounds__(256) void spmm_lvl_kernel(
        const unsigned short* __restrict__ in, const unsigned short* __restrict__ sub,
        unsigned short* __restrict__ out, float scale, int has_sub,
        const int* __restrict__ cnt, const int2* __restrict__ es) {
    int bx    = blockIdx.x;
    int slice = bx & 7;
    int rg    = bx >> 3;
    int wave  = threadIdx.x >> 6;
    int lane  = threadIdx.x & 63;
    int ep    = lane >> 5;
    int c     = lane & 31;
    int r     = rg * 4 + wave;
    int sc    = slice * 32 + c;

    u64 res = spmm_row(in, sub, scale, has_sub, cnt, es, r, sc, ep);
    if (ep == 0)
        ((u64*)out)[(size_t)r * 256 + sc] = res;   // normal store: keep slice in L2
}

// ---------------- merged: spmm level 4 (t4 = 2*L@t3 - t2) + MFMA GEMM ----------
// Column slice (128 cols) == batches 4s..4s+3 x all 32 channels; GEMM partitions
// by batch -> the block computing t4 for 16 rows x one slice owns exactly the t4
// its own GEMM tile needs (t4 via LDS only).
// NEW (round 4): the GEMM A-frags for k=0..2 (t0/t1/t2 -- HBM/L3-cold since the
// nontemporal sub-loads bypassed L2) are staged into LDS with global_load_lds
// ISSUED FIRST: in-order issue overlaps their ~900-cy miss latency with the
// whole phase-1 gather computation; the phase-1 __syncthreads (vmcnt drain) is
// the completion wait. t3 is L2-warm (just written) -> direct load.

__global__ __launch_bounds__(256) void spmm4_gemm_kernel(
        const unsigned short* __restrict__ t3, const unsigned short* __restrict__ t2,
        const unsigned short* __restrict__ tbase, const int* __restrict__ cnt,
        const int2* __restrict__ es, const unsigned short* __restrict__ WB,
        const float* __restrict__ bias, float* __restrict__ out) {
    __shared__ u64   t4l[16][33];          // +1 u64 pad: conflict-free b128 reads
    __shared__ s16x8 a_lds[4][3][64];      // [wave][k=0..2][lane] staged A-frags

    int tid  = threadIdx.x;
    int wv   = tid >> 6;                   // 0..3
    int lane = tid & 63;
    int bid  = blockIdx.x;                 // [0, 2048)
    int s    = bid & 7;                    // slice == XCD
    int n0   = (bid >> 3) << 4;            // node tile base, [0, 4096) step 16

    int m = lane & 15;
    int q = lane >> 4;
    int b = s * 4 + wv;                    // batch: b>>2 == slice -> slice-local A

    // ---- phase 0: async-stage t0/t1/t2 A-frags into LDS (issue-early) ----
    const unsigned short* abase = tbase + (size_t)(n0 + m) * BC + b * CIN + q * 8;
#pragma unroll
    for (int k = 0; k < 3; k++) {
        __builtin_amdgcn_global_load_lds(
            (const __attribute__((address_space(1))) unsigned int*)(abase + (size_t)k * TBF),
            (__attribute__((address_space(3))) unsigned int*)&a_lds[wv][k][0],
            16, 0, 0);
    }

    // ---- phase 1: t4 rows n0..n0+15, slice s -> LDS ----
    int ep = lane >> 5;
    int c  = lane & 31;
    int sc = s * 32 + c;
#pragma unroll
    for (int i = 0; i < 4; i++) {
        int r = n0 + i * 4 + wv;
        u64 res = spmm_row(t3, t2, 2.0f, 1, cnt, es, r, sc, ep);
        if (ep == 0)
            t4l[i * 4 + wv][c] = res;
    }
    __syncthreads();   // also drains the global_load_lds staging (vmcnt 0)

    // ---- phase 2: GEMM + bias + ReLU + maxpool for (b, node tile) ----
    f32x4 acc[4] = {{0.f,0.f,0.f,0.f},{0.f,0.f,0.f,0.f},
                    {0.f,0.f,0.f,0.f},{0.f,0.f,0.f,0.f}};

    const unsigned short* wbase = WB + m * 32 + q * 8;

#pragma unroll
    for (int k = 0; k < 3; k++) {          // k=0..2 from LDS (pre-staged)
        s16x8 a = a_lds[wv][k][lane];
#pragma unroll
        for (int ot = 0; ot < 4; ot++) {
            s16x8 bf = *(const s16x8*)(wbase + ((k * 64) + ot * 16) * 32);
            acc[ot] = __builtin_amdgcn_mfma_f32_16x16x32_bf16(a, bf, acc[ot], 0, 0, 0);
        }
    }
    {   // k=3 from global (t3: L2-warm, just written by spmm level 3)
        s16x8 a = *(const s16x8*)(abase + (size_t)3 * TBF);
#pragma unroll
        for (int ot = 0; ot < 4; ot++) {
            s16x8 bf = *(const s16x8*)(wbase + ((3 * 64) + ot * 16) * 32);
            acc[ot] = __builtin_amdgcn_mfma_f32_16x16x32_bf16(a, bf, acc[ot], 0, 0, 0);
        }
    }
    {   // k=4 from LDS (this block's own t4 sub-tile)
        union { u64 u[2]; s16x8 v; } cvt;
        cvt.u[0] = t4l[m][wv * 8 + q * 2];
        cvt.u[1] = t4l[m][wv * 8 + q * 2 + 1];
#pragma unroll
        for (int ot = 0; ot < 4; ot++) {
            s16x8 bf = *(const s16x8*)(wbase + ((4 * 64) + ot * 16) * 32);
            acc[ot] = __builtin_amdgcn_mfma_f32_16x16x32_bf16(cvt.v, bf, acc[ot], 0, 0, 0);
        }
    }

    size_t orow = ((size_t)b * (NNODE / POOL) + (n0 >> 2) + q) * COUT;
#pragma unroll
    for (int ot = 0; ot < 4; ot++) {
        float bi = bias[ot * 16 + m];
        float r0 = acc[ot][0] + bi; r0 = r0 > 0.f ? r0 : 0.f;
        float r1 = acc[ot][1] + bi; r1 = r1 > 0.f ? r1 : 0.f;
        float r2 = acc[ot][2] + bi; r2 = r2 > 0.f ? r2 : 0.f;
        float r3 = acc[ot][3] + bi; r3 = r3 > 0.f ? r3 : 0.f;
        float mx = r0 > r1 ? r0 : r1;
        mx = mx > r2 ? mx : r2;
        mx = mx > r3 ? mx : r3;
        out[orow + ot * 16 + m] = mx;
    }
}

// ---------------- launch: 6 dispatches, no intra-kernel global sync ------------

extern "C" void kernel_launch(void* const* d_in, const int* in_sizes, int n_in,
                              void* d_out, int out_size, void* d_ws, size_t ws_size,
                              hipStream_t stream) {
    const float* x    = (const float*)d_in[0];
    const float* eval = (const float*)d_in[1];
    const float* W    = (const float*)d_in[2];
    const float* bias = (const float*)d_in[3];
    const int*   erow = (const int*)d_in[4];
    const int*   ecol = (const int*)d_in[5];
    float* out = (float*)d_out;

    char* base = (char*)d_ws;
    unsigned short* tb = (unsigned short*)base;     // 4 levels x 8 MB (bf16); t4 in LDS
    unsigned short* t0 = tb;
    unsigned short* t1 = tb + 1 * TBF;
    unsigned short* t2 = tb + 2 * TBF;
    unsigned short* t3 = tb + 3 * TBF;

    size_t off = 5 * TBF * sizeof(unsigned short);  // keep layout (t4 slot unused)
    int2* es = (int2*)(base + off);  off += (size_t)NNODE * CAP * sizeof(int2);
    int* cnt = (int*)(base + off);   off += (size_t)NNODE * sizeof(int);
    off += 32 * sizeof(int);                        // legacy bar slot, unused
    off = (off + 63) & ~(size_t)63;
    unsigned short* WB = (unsigned short*)(base + off);

    // zero scatter cursors (d_ws re-poisoned every call -> rebuild each call)
    hipMemsetAsync(cnt, 0, NNODE * sizeof(int), stream);

    // transpose + W pack + bucket scatter (replaces prep+scan+scatter)
    prep2_kernel<<<TBF / 4 / 256, 256, 0, stream>>>(x, t0, erow, ecol, eval,
                                                    cnt, es, W, WB);

    // Chebyshev levels 1-3, column-sliced, bf16 storage / fp32 accumulate
    spmm_lvl_kernel<<<NNODE * 2, 256, 0, stream>>>(t0, nullptr, t1, 1.0f, 0, cnt, es);
    spmm_lvl_kernel<<<NNODE * 2, 256, 0, stream>>>(t1, t0, t2, 2.0f, 1, cnt, es);
    spmm_lvl_kernel<<<NNODE * 2, 256, 0, stream>>>(t2, t1, t3, 2.0f, 1, cnt, es);

    // level 4 fused into GEMM via LDS (slice == 4 batches -> block-local t4)
    spmm4_gemm_kernel<<<2048, 256, 0, stream>>>(t3, t2, tb, cnt, es, WB, bias, out);
}

// Round 5
// 176.109 us; speedup vs baseline: 1.1463x; 1.1463x over previous
//
#include <hip/hip_runtime.h>

// Problem constants
#define BATCH 32
#define NNODE 4096
#define CIN 32
#define COUT 64
#define KDEG 5
#define POOL 4
#define NNZ_E 65536
#define BC (BATCH * CIN)         // 1024 elems per node-row
#define TBF ((size_t)NNODE * BC) // elems per Chebyshev level (bf16 storage)
#define CAP 64                   // fixed bucket capacity per row (avg degree 16)

typedef short s16x8 __attribute__((ext_vector_type(8)));
typedef float f32x4 __attribute__((ext_vector_type(4)));
typedef unsigned long long u64;

// float -> bf16 bits, round-to-nearest-even
__device__ __forceinline__ unsigned short f2bf(float f) {
    union { float f; unsigned int u; } v; v.f = f;
    unsigned int u = v.u;
    u += 0x7fffu + ((u >> 16) & 1u);
    return (unsigned short)(u >> 16);
}
__device__ __forceinline__ float bf2f(unsigned short b) {
    union { float f; unsigned int u; } v; v.u = ((unsigned int)b) << 16;
    return v.f;
}
__device__ __forceinline__ u64 pack4(float a, float b, float c, float d) {
    return (u64)f2bf(a) | ((u64)f2bf(b) << 16) | ((u64)f2bf(c) << 32) | ((u64)f2bf(d) << 48);
}

// ---------------- prep2: transpose + W pack + capacity-bucket edge scatter -------
// (verified) Row r's edges land in es[r*64 .. r*64+cnt[r]) in arbitrary order
// (summation commutative). cnt zeroed by the preceding 16 KB memset.

__global__ void prep2_kernel(const float* __restrict__ x, unsigned short* __restrict__ t0,
                             const int* __restrict__ erow, const int* __restrict__ ecol,
                             const float* __restrict__ eval,
                             int* __restrict__ cnt, int2* __restrict__ es,
                             const float* __restrict__ W, unsigned short* __restrict__ WB) {
    int idx = blockIdx.x * 256 + threadIdx.x;   // [0, 1048576)
    // transpose [B][N][C] fp32 -> [N][B*C] bf16, 4 elems per thread
    int n   = idx >> 8;
    int rem = idx & 255;
    int b   = rem >> 3;
    int c4  = rem & 7;
    float4 v = ((const float4*)x)[(b * NNODE + n) * 8 + c4];
    ((u64*)t0)[idx] = pack4(v.x, v.y, v.z, v.w);

    if (idx < NNZ_E) {
        int r = erow[idx];
        int pos = atomicAdd(&cnt[r], 1);
        if (pos < CAP)
            es[(r << 6) + pos] = make_int2(ecol[idx], __float_as_int(eval[idx]));
    }

    if (idx < KDEG * COUT * CIN) {
        int c = idx & 31;
        int rest = idx >> 5;
        int o = rest & 63;
        int k = rest >> 6;
        // WB[k][o][c] : B-fragment order for mfma_16x16x32 (lane nn=o, kk=c)
        WB[idx] = f2bf(W[(c * KDEG + k) * COUT + o]);
    }
}

// ---------------- one (row, slice) unit of Chebyshev SpMM -- 4-ep layout --------
// Lanes = 4 edge-groups (ep = lane>>4) x 16 cols of 16B (c16 = lane&15).
// One 4-deep iteration puts all 16 edges of an average row in flight at once
// (4 es loads + 4 dwordx4 gathers; was 8+8 over 2 serial iterations).
// Gather stays perfectly coalesced: 16 lanes x 16B = 256B contiguous per edge.
// Returns the packed bf16x8 (16B) result on lanes 0..15 (ep==0).

__device__ __forceinline__ s16x8 spmm_row4(
        const unsigned short* in, const unsigned short* sub,
        float scale, int has_sub, const int* cnt, const int2* es,
        int r, int s, int lane) {
    int ep  = lane >> 4;               // edge-group 0..3
    int c16 = lane & 15;               // 16B col within slice (16 x 16B = 256B)
    const s16x8* in16 = (const s16x8*)in;   // row stride = 128 x 16B

    int deg = cnt[r]; deg = deg > CAP ? CAP : deg;
    int beg = r << 6, end = beg + deg;

    float acc[8] = {0.f,0.f,0.f,0.f,0.f,0.f,0.f,0.f};

    for (int base = beg + ep; base < end; base += 16) {
        float vv[4];
        s16x8 xx[4];
#pragma unroll
        for (int j = 0; j < 4; j++) {
            int idx = base + 4 * j;
            int src = idx < end ? idx : beg;   // beg valid: loop was entered
            int2 e = es[src];
            vv[j] = idx < end ? __int_as_float(e.y) : 0.f;
            xx[j] = in16[(size_t)e.x * 128 + s * 16 + c16];
        }
#pragma unroll
        for (int j = 0; j < 4; j++)
#pragma unroll
            for (int t = 0; t < 8; t++)
                acc[t] += vv[j] * bf2f((unsigned short)xx[j][t]);
    }

    // reduce across the 4 edge-groups (lane^16 then lane^32)
#pragma unroll
    for (int t = 0; t < 8; t++) {
        acc[t] += __shfl_xor(acc[t], 16);
        acc[t] += __shfl_xor(acc[t], 32);
    }

    union { u64 u[2]; s16x8 v; } res;
    res.u[0] = 0; res.u[1] = 0;
    if (ep == 0) {
        size_t oi = (size_t)r * 128 + s * 16 + c16;   // 16B units
        float rr[8];
        if (has_sub) {
            u64 sv0 = __builtin_nontemporal_load((const u64*)sub + 2 * oi);
            u64 sv1 = __builtin_nontemporal_load((const u64*)sub + 2 * oi + 1);
#pragma unroll
            for (int t = 0; t < 4; t++)
                rr[t] = scale * acc[t] - bf2f((unsigned short)(sv0 >> (16 * t)));
#pragma unroll
            for (int t = 0; t < 4; t++)
                rr[4 + t] = scale * acc[4 + t] - bf2f((unsigned short)(sv1 >> (16 * t)));
        } else {
#pragma unroll
            for (int t = 0; t < 8; t++) rr[t] = acc[t];
        }
        res.u[0] = pack4(rr[0], rr[1], rr[2], rr[3]);
        res.u[1] = pack4(rr[4], rr[5], rr[6], rr[7]);
    }
    return res.v;
}

// ---------------- standalone per-level SpMM (levels 1-3) ----------------
// grid = NNODE*2 = 8192 blocks; block = 4 rows x 1 slice (slice = bx&7 = XCD).

__global__ __launch_bounds__(256, 8) void spmm_lvl_kernel(
        const unsigned short* __restrict__ in, const unsigned short* __restrict__ sub,
        unsigned short* __restrict__ out, float scale, int has_sub,
        const int* __restrict__ cnt, const int2* __restrict__ es) {
    int bx    = blockIdx.x;
    int slice = bx & 7;
    int rg    = bx >> 3;
    int wave  = threadIdx.x >> 6;
    int lane  = threadIdx.x & 63;
    int r     = rg * 4 + wave;

    s16x8 res = spmm_row4(in, sub, scale, has_sub, cnt, es, r, slice, lane);
    if (lane < 16)
        ((s16x8*)out)[(size_t)r * 128 + slice * 16 + lane] = res;  // keep slice in L2
}

// ---------------- merged: spmm level 4 (t4 = 2*L@t3 - t2) + MFMA GEMM ----------
// 1024 threads = 16 waves: phase 1 does 1 row per wave (full SpMM parallelism --
// round-3/4's 4-sequential-rows-per-wave was the 55us bottleneck). Phase 2
// splits the GEMM 16 ways: wave = (batch 0..3) x (output quadrant 0..3); output
// columns are independent so no cross-wave reduction. t4 flows through LDS only.
// slice = bid&7 keeps t3/t2 gathers XCD-L2-local.

__global__ __launch_bounds__(1024, 8) void spmm4_gemm_kernel(
        const unsigned short* __restrict__ t3, const unsigned short* __restrict__ t2,
        const unsigned short* __restrict__ tbase, const int* __restrict__ cnt,
        const int2* __restrict__ es, const unsigned short* __restrict__ WB,
        const float* __restrict__ bias, float* __restrict__ out) {
    __shared__ s16x8 t4l[16][19];          // 16 rows x 16 slots of 16B (+3 pad)

    int tid  = threadIdx.x;
    int w    = tid >> 6;                   // wave 0..15
    int lane = tid & 63;
    int bid  = blockIdx.x;                 // [0, 2048)
    int s    = bid & 7;                    // slice == XCD
    int n0   = (bid >> 3) << 4;            // node tile base, [0, 4096) step 16

    // ---- phase 1: t4 row n0+w, slice s -> LDS (1 row per wave) ----
    {
        int r = n0 + w;
        s16x8 res = spmm_row4(t3, t2, 2.0f, 1, cnt, es, r, s, lane);
        if (lane < 16)
            t4l[w][lane] = res;
    }
    __syncthreads();

    // ---- phase 2: GEMM + bias + ReLU + maxpool; wave = (batch, out-quadrant) ----
    int m    = lane & 15;
    int q    = lane >> 4;
    int bsub = w & 3;
    int ot   = w >> 2;                     // output quadrant 0..3
    int b    = s * 4 + bsub;               // batch: b>>2 == slice -> slice-local A

    f32x4 acc = {0.f, 0.f, 0.f, 0.f};

    const unsigned short* abase = tbase + (size_t)(n0 + m) * BC + b * CIN + q * 8;
    const unsigned short* wbase = WB + m * 32 + q * 8 + (ot * 16) * 32;

#pragma unroll
    for (int k = 0; k < KDEG - 1; k++) {   // k=0..3 from global (t0..t3)
        s16x8 a = *(const s16x8*)(abase + (size_t)k * TBF);
        s16x8 bf = *(const s16x8*)(wbase + (k * 64) * 32);
        acc = __builtin_amdgcn_mfma_f32_16x16x32_bf16(a, bf, acc, 0, 0, 0);
    }
    {   // k=4 from LDS (this block's own t4 sub-tile)
        s16x8 a = t4l[m][bsub * 4 + q];
        s16x8 bf = *(const s16x8*)(wbase + (4 * 64) * 32);
        acc = __builtin_amdgcn_mfma_f32_16x16x32_bf16(a, bf, acc, 0, 0, 0);
    }

    size_t orow = ((size_t)b * (NNODE / POOL) + (n0 >> 2) + q) * COUT;
    float bi = bias[ot * 16 + m];
    float r0 = acc[0] + bi; r0 = r0 > 0.f ? r0 : 0.f;
    float r1 = acc[1] + bi; r1 = r1 > 0.f ? r1 : 0.f;
    float r2 = acc[2] + bi; r2 = r2 > 0.f ? r2 : 0.f;
    float r3 = acc[3] + bi; r3 = r3 > 0.f ? r3 : 0.f;
    float mx = r0 > r1 ? r0 : r1;
    mx = mx > r2 ? mx : r2;
    mx = mx > r3 ? mx : r3;
    out[orow + ot * 16 + m] = mx;
}

// ---------------- launch: 6 dispatches, no intra-kernel global sync ------------

extern "C" void kernel_launch(void* const* d_in, const int* in_sizes, int n_in,
                              void* d_out, int out_size, void* d_ws, size_t ws_size,
                              hipStream_t stream) {
    const float* x    = (const float*)d_in[0];
    const float* eval = (const float*)d_in[1];
    const float* W    = (const float*)d_in[2];
    const float* bias = (const float*)d_in[3];
    const int*   erow = (const int*)d_in[4];
    const int*   ecol = (const int*)d_in[5];
    float* out = (float*)d_out;

    char* base = (char*)d_ws;
    unsigned short* tb = (unsigned short*)base;     // 4 levels x 8 MB (bf16); t4 in LDS
    unsigned short* t0 = tb;
    unsigned short* t1 = tb + 1 * TBF;
    unsigned short* t2 = tb + 2 * TBF;
    unsigned short* t3 = tb + 3 * TBF;

    size_t off = 5 * TBF * sizeof(unsigned short);  // keep layout (t4 slot unused)
    int2* es = (int2*)(base + off);  off += (size_t)NNODE * CAP * sizeof(int2);
    int* cnt = (int*)(base + off);   off += (size_t)NNODE * sizeof(int);
    off += 32 * sizeof(int);                        // legacy bar slot, unused
    off = (off + 63) & ~(size_t)63;
    unsigned short* WB = (unsigned short*)(base + off);

    // zero scatter cursors (d_ws re-poisoned every call -> rebuild each call)
    hipMemsetAsync(cnt, 0, NNODE * sizeof(int), stream);

    // transpose + W pack + bucket scatter (replaces prep+scan+scatter)
    prep2_kernel<<<TBF / 4 / 256, 256, 0, stream>>>(x, t0, erow, ecol, eval,
                                                    cnt, es, W, WB);

    // Chebyshev levels 1-3, column-sliced, bf16 storage / fp32 accumulate
    spmm_lvl_kernel<<<NNODE * 2, 256, 0, stream>>>(t0, nullptr, t1, 1.0f, 0, cnt, es);
    spmm_lvl_kernel<<<NNODE * 2, 256, 0, stream>>>(t1, t0, t2, 2.0f, 1, cnt, es);
    spmm_lvl_kernel<<<NNODE * 2, 256, 0, stream>>>(t2, t1, t3, 2.0f, 1, cnt, es);

    // level 4 fused into GEMM via LDS; 16 waves: full phase-1 parallelism
    spmm4_gemm_kernel<<<2048, 1024, 0, stream>>>(t3, t2, tb, cnt, es, WB, bias, out);
}

// Round 6
// 166.332 us; speedup vs baseline: 1.2137x; 1.0588x over previous
//
#include <hip/hip_runtime.h>

// Problem constants
#define BATCH 32
#define NNODE 4096
#define CIN 32
#define COUT 64
#define KDEG 5
#define POOL 4
#define NNZ_E 65536
#define BC (BATCH * CIN)         // 1024 elems per node-row
#define TBF ((size_t)NNODE * BC) // elems per Chebyshev level (bf16 storage)
#define CAP 64                   // fixed bucket capacity per row (avg degree 16)

typedef short s16x8 __attribute__((ext_vector_type(8)));
typedef float f32x4 __attribute__((ext_vector_type(4)));
typedef unsigned long long u64;

// float -> bf16 bits, round-to-nearest-even
__device__ __forceinline__ unsigned short f2bf(float f) {
    union { float f; unsigned int u; } v; v.f = f;
    unsigned int u = v.u;
    u += 0x7fffu + ((u >> 16) & 1u);
    return (unsigned short)(u >> 16);
}
__device__ __forceinline__ float bf2f(unsigned short b) {
    union { float f; unsigned int u; } v; v.u = ((unsigned int)b) << 16;
    return v.f;
}
__device__ __forceinline__ u64 pack4(float a, float b, float c, float d) {
    return (u64)f2bf(a) | ((u64)f2bf(b) << 16) | ((u64)f2bf(c) << 32) | ((u64)f2bf(d) << 48);
}

// ---------------- prep2: transpose + W pack + capacity-bucket edge scatter -------
// (verified) Row r's edges land in es[r*64 .. r*64+cnt[r]) in arbitrary order
// (summation commutative). cnt zeroed by the preceding 16 KB memset.

__global__ void prep2_kernel(const float* __restrict__ x, unsigned short* __restrict__ t0,
                             const int* __restrict__ erow, const int* __restrict__ ecol,
                             const float* __restrict__ eval,
                             int* __restrict__ cnt, int2* __restrict__ es,
                             const float* __restrict__ W, unsigned short* __restrict__ WB) {
    int idx = blockIdx.x * 256 + threadIdx.x;   // [0, 1048576)
    // transpose [B][N][C] fp32 -> [N][B*C] bf16, 4 elems per thread
    int n   = idx >> 8;
    int rem = idx & 255;
    int b   = rem >> 3;
    int c4  = rem & 7;
    float4 v = ((const float4*)x)[(b * NNODE + n) * 8 + c4];
    ((u64*)t0)[idx] = pack4(v.x, v.y, v.z, v.w);

    if (idx < NNZ_E) {
        int r = erow[idx];
        int pos = atomicAdd(&cnt[r], 1);
        if (pos < CAP)
            es[(r << 6) + pos] = make_int2(ecol[idx], __float_as_int(eval[idx]));
    }

    if (idx < KDEG * COUT * CIN) {
        int c = idx & 31;
        int rest = idx >> 5;
        int o = rest & 63;
        int k = rest >> 6;
        // WB[k][o][c] : B-fragment order for mfma_16x16x32 (lane nn=o, kk=c)
        WB[idx] = f2bf(W[(c * KDEG + k) * COUT + o]);
    }
}

// ---------------- one (row, slice) unit of Chebyshev SpMM -- 4-ep layout --------
// (verified round 5) Lanes = 4 edge-groups (ep = lane>>4) x 16 cols of 16B.
// One 4-deep iteration puts all 16 edges of an average row in flight at once.
// Gather coalesced: 16 lanes x 16B = 256B contiguous per edge.
// CHANGE (round 6): sub loads are NORMAL (not nontemporal) -- keeps t_{k-1}
// slices L2-resident for the GEMM's A-reads (was 21 MB of HBM re-fetch).
// Returns the packed bf16x8 (16B) result on lanes 0..15 (ep==0).

__device__ __forceinline__ s16x8 spmm_row4(
        const unsigned short* in, const unsigned short* sub,
        float scale, int has_sub, const int* cnt, const int2* es,
        int r, int s, int lane) {
    int ep  = lane >> 4;               // edge-group 0..3
    int c16 = lane & 15;               // 16B col within slice (16 x 16B = 256B)
    const s16x8* in16 = (const s16x8*)in;   // row stride = 128 x 16B

    int deg = cnt[r]; deg = deg > CAP ? CAP : deg;
    int beg = r << 6, end = beg + deg;

    float acc[8] = {0.f,0.f,0.f,0.f,0.f,0.f,0.f,0.f};

    for (int base = beg + ep; base < end; base += 16) {
        float vv[4];
        s16x8 xx[4];
#pragma unroll
        for (int j = 0; j < 4; j++) {
            int idx = base + 4 * j;
            int src = idx < end ? idx : beg;   // beg valid: loop was entered
            int2 e = es[src];
            vv[j] = idx < end ? __int_as_float(e.y) : 0.f;
            xx[j] = in16[(size_t)e.x * 128 + s * 16 + c16];
        }
#pragma unroll
        for (int j = 0; j < 4; j++)
#pragma unroll
            for (int t = 0; t < 8; t++)
                acc[t] += vv[j] * bf2f((unsigned short)xx[j][t]);
    }

    // reduce across the 4 edge-groups (lane^16 then lane^32)
#pragma unroll
    for (int t = 0; t < 8; t++) {
        acc[t] += __shfl_xor(acc[t], 16);
        acc[t] += __shfl_xor(acc[t], 32);
    }

    union { u64 u[2]; s16x8 v; } res;
    res.u[0] = 0; res.u[1] = 0;
    if (ep == 0) {
        size_t oi = (size_t)r * 128 + s * 16 + c16;   // 16B units
        float rr[8];
        if (has_sub) {
            u64 sv0 = ((const u64*)sub)[2 * oi];
            u64 sv1 = ((const u64*)sub)[2 * oi + 1];
#pragma unroll
            for (int t = 0; t < 4; t++)
                rr[t] = scale * acc[t] - bf2f((unsigned short)(sv0 >> (16 * t)));
#pragma unroll
            for (int t = 0; t < 4; t++)
                rr[4 + t] = scale * acc[4 + t] - bf2f((unsigned short)(sv1 >> (16 * t)));
        } else {
#pragma unroll
            for (int t = 0; t < 8; t++) rr[t] = acc[t];
        }
        res.u[0] = pack4(rr[0], rr[1], rr[2], rr[3]);
        res.u[1] = pack4(rr[4], rr[5], rr[6], rr[7]);
    }
    return res.v;
}

// ---------------- standalone per-level SpMM (levels 1-4) ----------------
// grid = NNODE*2 = 8192 blocks of 256; block = 4 rows x 1 slice
// (slice = bx&7 = XCD -- the pinning that makes gathers L2-local).

__global__ __launch_bounds__(256, 8) void spmm_lvl_kernel(
        const unsigned short* __restrict__ in, const unsigned short* __restrict__ sub,
        unsigned short* __restrict__ out, float scale, int has_sub,
        const int* __restrict__ cnt, const int2* __restrict__ es) {
    int bx    = blockIdx.x;
    int slice = bx & 7;
    int rg    = bx >> 3;
    int wave  = threadIdx.x >> 6;
    int lane  = threadIdx.x & 63;
    int r     = rg * 4 + wave;

    s16x8 res = spmm_row4(in, sub, scale, has_sub, cnt, es, r, slice, lane);
    if (lane < 16)
        ((s16x8*)out)[(size_t)r * 128 + slice * 16 + lane] = res;  // keep slice in L2
}

// ---------------- MFMA GEMM + bias + ReLU + maxpool (verified round 0) ---------
// One wave = one (batch b, 16-node tile). D row = quad*4+r -> lane's 4 acc rows
// are exactly one pool group; ReLU+maxpool collapse to in-lane max. No LDS.

__global__ __launch_bounds__(256) void gemm_mfma_pool_kernel(
        const unsigned short* __restrict__ tbase, const unsigned short* __restrict__ WB,
        const float* __restrict__ bias, float* __restrict__ out) {
    int gtid = blockIdx.x * 256 + threadIdx.x;
    int lane = threadIdx.x & 63;
    int wid  = gtid >> 6;            // [0, 8192)
    int b    = wid >> 8;             // [0, 32)
    int n0   = (wid & 255) << 4;     // node tile base
    int m    = lane & 15;
    int q    = lane >> 4;

    f32x4 acc[4] = {{0.f,0.f,0.f,0.f},{0.f,0.f,0.f,0.f},
                    {0.f,0.f,0.f,0.f},{0.f,0.f,0.f,0.f}};

    const unsigned short* abase = tbase + (size_t)(n0 + m) * BC + b * CIN + q * 8;
    const unsigned short* wbase = WB + m * 32 + q * 8;

#pragma unroll
    for (int k = 0; k < KDEG; k++) {
        s16x8 a = *(const s16x8*)(abase + (size_t)k * TBF);
#pragma unroll
        for (int ot = 0; ot < 4; ot++) {
            s16x8 bf = *(const s16x8*)(wbase + ((k * 64) + ot * 16) * 32);
            acc[ot] = __builtin_amdgcn_mfma_f32_16x16x32_bf16(a, bf, acc[ot], 0, 0, 0);
        }
    }

    size_t orow = ((size_t)b * (NNODE / POOL) + (n0 >> 2) + q) * COUT;
#pragma unroll
    for (int ot = 0; ot < 4; ot++) {
        float bi = bias[ot * 16 + m];
        float r0 = acc[ot][0] + bi; r0 = r0 > 0.f ? r0 : 0.f;
        float r1 = acc[ot][1] + bi; r1 = r1 > 0.f ? r1 : 0.f;
        float r2 = acc[ot][2] + bi; r2 = r2 > 0.f ? r2 : 0.f;
        float r3 = acc[ot][3] + bi; r3 = r3 > 0.f ? r3 : 0.f;
        float mx = r0 > r1 ? r0 : r1;
        mx = mx > r2 ? mx : r2;
        mx = mx > r3 ? mx : r3;
        out[orow + ot * 16 + m] = mx;
    }
}

// ---------------- launch: 7 dispatches ----------------

extern "C" void kernel_launch(void* const* d_in, const int* in_sizes, int n_in,
                              void* d_out, int out_size, void* d_ws, size_t ws_size,
                              hipStream_t stream) {
    const float* x    = (const float*)d_in[0];
    const float* eval = (const float*)d_in[1];
    const float* W    = (const float*)d_in[2];
    const float* bias = (const float*)d_in[3];
    const int*   erow = (const int*)d_in[4];
    const int*   ecol = (const int*)d_in[5];
    float* out = (float*)d_out;

    char* base = (char*)d_ws;
    unsigned short* tb = (unsigned short*)base;     // 5 levels x 8 MB (bf16)
    unsigned short* t0 = tb;
    unsigned short* t1 = tb + 1 * TBF;
    unsigned short* t2 = tb + 2 * TBF;
    unsigned short* t3 = tb + 3 * TBF;
    unsigned short* t4 = tb + 4 * TBF;

    size_t off = 5 * TBF * sizeof(unsigned short);
    int2* es = (int2*)(base + off);  off += (size_t)NNODE * CAP * sizeof(int2);
    int* cnt = (int*)(base + off);   off += (size_t)NNODE * sizeof(int);
    off += 32 * sizeof(int);                        // legacy bar slot, unused
    off = (off + 63) & ~(size_t)63;
    unsigned short* WB = (unsigned short*)(base + off);

    // zero scatter cursors (d_ws re-poisoned every call -> rebuild each call)
    hipMemsetAsync(cnt, 0, NNODE * sizeof(int), stream);

    // transpose + W pack + bucket scatter
    prep2_kernel<<<TBF / 4 / 256, 256, 0, stream>>>(x, t0, erow, ecol, eval,
                                                    cnt, es, W, WB);

    // Chebyshev levels 1-4, column-sliced, bf16 storage / fp32 accumulate
    spmm_lvl_kernel<<<NNODE * 2, 256, 0, stream>>>(t0, nullptr, t1, 1.0f, 0, cnt, es);
    spmm_lvl_kernel<<<NNODE * 2, 256, 0, stream>>>(t1, t0, t2, 2.0f, 1, cnt, es);
    spmm_lvl_kernel<<<NNODE * 2, 256, 0, stream>>>(t2, t1, t3, 2.0f, 1, cnt, es);
    spmm_lvl_kernel<<<NNODE * 2, 256, 0, stream>>>(t3, t2, t4, 2.0f, 1, cnt, es);

    // MFMA GEMM + bias + relu + maxpool
    gemm_mfma_pool_kernel<<<(BATCH * (NNODE / 16) * 64) / 256, 256, 0, stream>>>(
        tb, WB, bias, out);
}